// Round 1
// baseline (2781.751 us; speedup 1.0000x reference)
//
#include <hip/hip_runtime.h>

#define NB 8
#define NPTS 4160
#define NS 1024
#define KS 32
#define NROWS (NB*NS*KS)   /* 262144 */
#define R2 0.25f

__device__ __forceinline__ float fmul_(float a, float b){ return __fmul_rn(a,b); }
__device__ __forceinline__ float fadd_(float a, float b){ return __fadd_rn(a,b); }

// ---------------- init: zero stats region ----------------
__global__ void k_init(float* stats) {
  stats[threadIdx.x] = 0.f;
}

// ---------------- FPS: one block per batch ----------------
__global__ __launch_bounds__(1024) void k_fps(const float* __restrict__ xyz,
                                              float* __restrict__ out_nx) {
  __shared__ float xyzs[NPTS*3];
  __shared__ float s_rv[16];
  __shared__ int   s_ri[16];
  __shared__ int   s_widx;
  int b = blockIdx.x;
  int tid = threadIdx.x;
  const float* X = xyz + (size_t)b*NPTS*3;
  for (int i = tid; i < NPTS*3; i += 1024) xyzs[i] = X[i];
  float px[5], py[5], pz[5], dmin[5];
#pragma unroll
  for (int k = 0; k < 5; ++k) {
    int i = tid + (k<<10);
    if (k < 4 || tid < (NPTS - 4096)) {
      px[k] = X[i*3]; py[k] = X[i*3+1]; pz[k] = X[i*3+2];
      dmin[k] = 1e10f;
    } else { px[k]=0.f; py[k]=0.f; pz[k]=0.f; dmin[k] = -1.f; }
  }
  if (tid == 0) {
    s_widx = 0;
    out_nx[(size_t)b*NS*3]   = X[0];
    out_nx[(size_t)b*NS*3+1] = X[1];
    out_nx[(size_t)b*NS*3+2] = X[2];
  }
  __syncthreads();
  for (int it = 1; it < NS; ++it) {
    int w = s_widx;
    float cx = xyzs[w*3], cy = xyzs[w*3+1], cz = xyzs[w*3+2];
    float best = -1.f; int bidx = 0x7fffffff;
#pragma unroll
    for (int k = 0; k < 5; ++k) {
      if (k < 4 || tid < (NPTS - 4096)) {
        float dx = px[k]-cx, dy = py[k]-cy, dz = pz[k]-cz;
        float d = fadd_(fadd_(fmul_(dx,dx), fmul_(dy,dy)), fmul_(dz,dz));
        float dm = fminf(dmin[k], d);
        dmin[k] = dm;
        if (dm > best) { best = dm; bidx = tid + (k<<10); }
      }
    }
#pragma unroll
    for (int off = 32; off >= 1; off >>= 1) {
      float ov = __shfl_down(best, off);
      int   oi = __shfl_down(bidx, off);
      if (ov > best || (ov == best && oi < bidx)) { best = ov; bidx = oi; }
    }
    int wid = tid >> 6;
    if ((tid & 63) == 0) { s_rv[wid] = best; s_ri[wid] = bidx; }
    __syncthreads();
    if (tid < 64) {
      float v  = (tid < 16) ? s_rv[tid] : -1.f;
      int   ix = (tid < 16) ? s_ri[tid] : 0x7fffffff;
#pragma unroll
      for (int off = 8; off >= 1; off >>= 1) {
        float ov = __shfl_down(v, off);
        int   oi = __shfl_down(ix, off);
        if (ov > v || (ov == v && oi < ix)) { v = ov; ix = oi; }
      }
      if (tid == 0) s_widx = ix;
    }
    __syncthreads();
    if (tid == 0) {
      int nw = s_widx;
      size_t o = (size_t)b*NS*3 + (size_t)it*3;
      out_nx[o] = xyzs[nw*3]; out_nx[o+1] = xyzs[nw*3+1]; out_nx[o+2] = xyzs[nw*3+2];
    }
  }
}

// ---------------- ball query: one wave per query ----------------
__global__ __launch_bounds__(256) void k_query(const float* __restrict__ xyz,
    const float* __restrict__ nx, int* __restrict__ gidx) {
  int gt = blockIdx.x*256 + threadIdx.x;
  int gw = gt >> 6;
  int lane = threadIdx.x & 63;
  int b = gw >> 10;
  const float* X = xyz + (size_t)b*NPTS*3;
  float qx = nx[(size_t)gw*3], qy = nx[(size_t)gw*3+1], qz = nx[(size_t)gw*3+2];
  float qsq = fadd_(fadd_(fmul_(qx,qx), fmul_(qy,qy)), fmul_(qz,qz));
  float ld = 3.0e38f; int li = 0x7fffffff;     // sorted list in lanes 0..31
  for (int c0 = 0; c0 < NPTS; c0 += 64) {
    int p = c0 + lane;
    float d = 3.3e38f; int pi = 0x7fffffff;
    if (p < NPTS) {
      float x = X[p*3], yv = X[p*3+1], z = X[p*3+2];
      float psq = fadd_(fadd_(fmul_(x,x), fmul_(yv,yv)), fmul_(z,z));
      float dot = fadd_(fadd_(fmul_(x,qx), fmul_(yv,qy)), fmul_(z,qz));
      d = fadd_(fadd_(fmul_(-2.f,dot), qsq), psq);
      pi = p;
    }
    float c31d = __shfl(ld, 31); int c31i = __shfl(li, 31);
    bool candp = (d < c31d) || (d == c31d && pi < c31i);
    unsigned long long bm = __ballot(candp);
    while (bm) {
      int src = __builtin_ctzll(bm);
      bm &= bm - 1;
      float cd = __shfl(d, src);
      int   ci = __shfl(pi, src);
      bool lt = (cd < ld) || (cd == ld && ci < li);
      unsigned long long im = __ballot(lt) & 0xffffffffull;
      float sd = __shfl_up(ld, 1);
      int   si = __shfl_up(li, 1);
      if (im) {
        int pos = __builtin_ctzll(im);
        if (lane < 32 && lt) {
          ld = (lane == pos) ? cd : sd;
          li = (lane == pos) ? ci : si;
        }
      }
    }
  }
  int i0 = __shfl(li, 0);
  if (lane < KS) {
    gidx[(size_t)gw*KS + lane] = (ld > R2) ? i0 : li;
  }
}

// ---------------- pointwise-conv helpers ----------------
__device__ __forceinline__ void doc(float* acc, const float4* sW4, int c, float rc) {
#pragma unroll
  for (int o4 = 0; o4 < 16; ++o4) {
    float4 w = sW4[c*16 + o4];
    acc[o4*4]   = fmaf(rc, w.x, acc[o4*4]);
    acc[o4*4+1] = fmaf(rc, w.y, acc[o4*4+1]);
    acc[o4*4+2] = fmaf(rc, w.z, acc[o4*4+2]);
    acc[o4*4+3] = fmaf(rc, w.w, acc[o4*4+3]);
  }
}

__device__ __forceinline__ void doc2(float* a, const float4* sW4, int c, int o0, float rc) {
  float4 w0 = sW4[c*32 + (o0>>2)];
  float4 w1 = sW4[c*32 + (o0>>2) + 1];
  a[0]=fmaf(rc,w0.x,a[0]); a[1]=fmaf(rc,w0.y,a[1]); a[2]=fmaf(rc,w0.z,a[2]); a[3]=fmaf(rc,w0.w,a[3]);
  a[4]=fmaf(rc,w1.x,a[4]); a[5]=fmaf(rc,w1.y,a[5]); a[6]=fmaf(rc,w1.z,a[6]); a[7]=fmaf(rc,w1.w,a[7]);
}

// ---------------- layer 0: gather + conv(67->64) + stats ----------------
__global__ __launch_bounds__(256) void k_layer0(
    const float* __restrict__ xyz, const float* __restrict__ pts,
    const float* __restrict__ nx, const int* __restrict__ gidx,
    const float* __restrict__ W, const float* __restrict__ bias,
    float* __restrict__ y, float* __restrict__ stats) {
  __shared__ float4 sW4[67*16];
  __shared__ float sB[64];
  __shared__ float sStat[128];
  float* sW = (float*)sW4;
  int tid = threadIdx.x;
  for (int i = tid; i < 67*64; i += 256) {
    int c = i >> 6, o = i & 63;
    sW[i] = W[o*67 + c];
  }
  if (tid < 64) sB[tid] = bias[tid];
  if (tid < 128) sStat[tid] = 0.f;
  __syncthreads();
  int row = blockIdx.x*256 + tid;
  int b = row >> 15;
  int j = gidx[row];
  size_t q = (size_t)(row >> 5);
  float qx = nx[q*3], qy = nx[q*3+1], qz = nx[q*3+2];
  size_t pb = (size_t)b*NPTS + j;
  float acc[64];
#pragma unroll
  for (int o = 0; o < 64; ++o) acc[o] = sB[o];
  {
    float r0 = xyz[pb*3]   - qx;
    float r1 = xyz[pb*3+1] - qy;
    float r2 = xyz[pb*3+2] - qz;
    doc(acc, sW4, 0, r0); doc(acc, sW4, 1, r1); doc(acc, sW4, 2, r2);
  }
  const float4* P4 = (const float4*)(pts + pb*64);
  for (int c4 = 0; c4 < 16; ++c4) {
    float4 v = P4[c4];
    int c = 3 + c4*4;
    doc(acc, sW4, c, v.x); doc(acc, sW4, c+1, v.y);
    doc(acc, sW4, c+2, v.z); doc(acc, sW4, c+3, v.w);
  }
  float4* Y4 = (float4*)(y + (size_t)row*64);
#pragma unroll
  for (int o4 = 0; o4 < 16; ++o4)
    Y4[o4] = make_float4(acc[o4*4], acc[o4*4+1], acc[o4*4+2], acc[o4*4+3]);
#pragma unroll
  for (int o = 0; o < 64; ++o) {
    atomicAdd(&sStat[o], acc[o]);
    atomicAdd(&sStat[64+o], fmul_(acc[o],acc[o]));
  }
  __syncthreads();
  if (tid < 128) atomicAdd(&stats[tid], sStat[tid]);
}

// ---------------- layer 1: BN+relu + conv(64->64) in-place + stats ----------------
__global__ __launch_bounds__(256) void k_layer1(
    float* __restrict__ y, const float* __restrict__ W,
    const float* __restrict__ bias, float* stats) {
  __shared__ float4 sW4[64*16];
  __shared__ float sB[64], sSc[64], sSh[64];
  __shared__ float sStat[128];
  float* sW = (float*)sW4;
  int tid = threadIdx.x;
  for (int i = tid; i < 64*64; i += 256) {
    int c = i >> 6, o = i & 63;
    sW[i] = W[o*64 + c];
  }
  if (tid < 64) { sB[tid]=bias[tid]; sSc[tid]=stats[512+tid]; sSh[tid]=stats[576+tid]; }
  if (tid < 128) sStat[tid] = 0.f;
  __syncthreads();
  int row = blockIdx.x*256 + tid;
  float4* Y4 = (float4*)(y + (size_t)row*64);
  float acc[64];
#pragma unroll
  for (int o = 0; o < 64; ++o) acc[o] = sB[o];
  for (int c4 = 0; c4 < 16; ++c4) {
    float4 v = Y4[c4];
    int c = c4*4;
    doc(acc, sW4, c,   fmaxf(fmaf(v.x, sSc[c],   sSh[c]),   0.f));
    doc(acc, sW4, c+1, fmaxf(fmaf(v.y, sSc[c+1], sSh[c+1]), 0.f));
    doc(acc, sW4, c+2, fmaxf(fmaf(v.z, sSc[c+2], sSh[c+2]), 0.f));
    doc(acc, sW4, c+3, fmaxf(fmaf(v.w, sSc[c+3], sSh[c+3]), 0.f));
  }
#pragma unroll
  for (int o4 = 0; o4 < 16; ++o4)
    Y4[o4] = make_float4(acc[o4*4], acc[o4*4+1], acc[o4*4+2], acc[o4*4+3]);
#pragma unroll
  for (int o = 0; o < 64; ++o) {
    atomicAdd(&sStat[o], acc[o]);
    atomicAdd(&sStat[64+o], fmul_(acc[o],acc[o]));
  }
  __syncthreads();
  if (tid < 128) atomicAdd(&stats[128+tid], sStat[tid]);
}

// ---------------- layer 2: BN+relu + conv(64->128) + stats + max/min pool ----------------
__global__ __launch_bounds__(256) void k_layer2(
    const float* __restrict__ y, const float* __restrict__ W,
    const float* __restrict__ bias, float* stats,
    float* __restrict__ pmax, float* __restrict__ pmin) {
  __shared__ float4 sW4[64*32];
  __shared__ float sB[128], sSc[64], sSh[64];
  __shared__ float sStat[256];
  float* sW = (float*)sW4;
  int tid = threadIdx.x;
  for (int i = tid; i < 64*128; i += 256) {
    int c = i >> 7, o = i & 127;
    sW[i] = W[o*64 + c];
  }
  if (tid < 128) sB[tid] = bias[tid];
  if (tid < 64) { sSc[tid] = stats[640+tid]; sSh[tid] = stats[704+tid]; }
  sStat[tid] = 0.f;
  __syncthreads();
  int t = blockIdx.x*256 + tid;
  int g = t >> 4;
  int o0 = (t & 15) * 8;
  float mx[8], mn[8], sm[8], sq[8];
#pragma unroll
  for (int i=0;i<8;++i){ mx[i]=-3.4e38f; mn[i]=3.4e38f; sm[i]=0.f; sq[i]=0.f; }
  const float4* Y4 = (const float4*)(y) + (size_t)g*32*16;
  for (int n = 0; n < 32; ++n) {
    float a[8];
#pragma unroll
    for (int i=0;i<8;++i) a[i] = sB[o0+i];
    for (int c4 = 0; c4 < 16; ++c4) {
      float4 v = Y4[n*16 + c4];
      int c = c4*4;
      doc2(a, sW4, c,   o0, fmaxf(fmaf(v.x, sSc[c],   sSh[c]),   0.f));
      doc2(a, sW4, c+1, o0, fmaxf(fmaf(v.y, sSc[c+1], sSh[c+1]), 0.f));
      doc2(a, sW4, c+2, o0, fmaxf(fmaf(v.z, sSc[c+2], sSh[c+2]), 0.f));
      doc2(a, sW4, c+3, o0, fmaxf(fmaf(v.w, sSc[c+3], sSh[c+3]), 0.f));
    }
#pragma unroll
    for (int i=0;i<8;++i) {
      mx[i]=fmaxf(mx[i],a[i]); mn[i]=fminf(mn[i],a[i]);
      sm[i]=fadd_(sm[i],a[i]); sq[i]=fmaf(a[i],a[i],sq[i]);
    }
  }
  size_t ob = (size_t)g*128 + o0;
#pragma unroll
  for (int i=0;i<8;++i) { pmax[ob+i]=mx[i]; pmin[ob+i]=mn[i]; }
#pragma unroll
  for (int i=0;i<8;++i) {
    atomicAdd(&sStat[o0+i], sm[i]);
    atomicAdd(&sStat[128+o0+i], sq[i]);
  }
  __syncthreads();
  atomicAdd(&stats[256+tid], sStat[tid]);
}

// ---------------- BN finalize ----------------
__global__ void k_fin(float* stats, const float* g, const float* bb,
                      int cout, int soff, int ooff) {
  int o = threadIdx.x;
  if (o >= cout) return;
  float s = stats[soff + o], s2 = stats[soff + cout + o];
  float mean = s * (1.0f/262144.0f);
  float var = fmaxf(s2 * (1.0f/262144.0f) - mean*mean, 0.f);
  float sc = g[o] / sqrtf(var + 1e-5f);
  stats[ooff + o] = sc;
  stats[ooff + cout + o] = bb[o] - mean * sc;
}

// ---------------- output: BN+relu on pooled ----------------
__global__ __launch_bounds__(256) void k_out(const float* __restrict__ pmax,
    const float* __restrict__ pmin, const float* __restrict__ stats,
    float* __restrict__ outp) {
  int t = blockIdx.x*256 + threadIdx.x;
  int o = t & 127;
  float sc = stats[768+o], sh = stats[896+o];
  float sel = (sc >= 0.f) ? pmax[t] : pmin[t];
  outp[t] = fmaxf(fmaf(sel, sc, sh), 0.f);
}

extern "C" void kernel_launch(void* const* d_in, const int* in_sizes, int n_in,
                              void* d_out, int out_size, void* d_ws, size_t ws_size,
                              hipStream_t stream) {
  const float* xyz = (const float*)d_in[0];
  const float* pts = (const float*)d_in[1];
  const float* W0  = (const float*)d_in[2];
  const float* b0  = (const float*)d_in[3];
  const float* g0  = (const float*)d_in[4];
  const float* bb0 = (const float*)d_in[5];
  const float* W1  = (const float*)d_in[6];
  const float* b1  = (const float*)d_in[7];
  const float* g1  = (const float*)d_in[8];
  const float* bb1 = (const float*)d_in[9];
  const float* W2  = (const float*)d_in[10];
  const float* b2  = (const float*)d_in[11];
  const float* g2  = (const float*)d_in[12];
  const float* bb2 = (const float*)d_in[13];
  float* out_nx = (float*)d_out;
  float* out_np = out_nx + (size_t)NB*NS*3;
  float* ws = (float*)d_ws;
  float* stats = ws;                               // 1024 floats
  int* gidx = (int*)(ws + 1024);                   // NROWS ints
  float* ybuf = ws + 1024 + NROWS;                 // NROWS*64 floats
  float* pmax = ybuf + (size_t)NROWS*64;           // NB*NS*128
  float* pmin = pmax + (size_t)NB*NS*128;          // NB*NS*128

  k_init<<<1, 1024, 0, stream>>>(stats);
  k_fps<<<NB, 1024, 0, stream>>>(xyz, out_nx);
  k_query<<<2048, 256, 0, stream>>>(xyz, out_nx, gidx);
  k_layer0<<<1024, 256, 0, stream>>>(xyz, pts, out_nx, gidx, W0, b0, ybuf, stats);
  k_fin<<<1, 128, 0, stream>>>(stats, g0, bb0, 64, 0, 512);
  k_layer1<<<1024, 256, 0, stream>>>(ybuf, W1, b1, stats);
  k_fin<<<1, 128, 0, stream>>>(stats, g1, bb1, 64, 128, 640);
  k_layer2<<<512, 256, 0, stream>>>(ybuf, W2, b2, stats, pmax, pmin);
  k_fin<<<1, 128, 0, stream>>>(stats, g2, bb2, 128, 256, 768);
  k_out<<<4096, 256, 0, stream>>>(pmax, pmin, stats, out_np);
}

// Round 2
// 2368.170 us; speedup vs baseline: 1.1746x; 1.1746x over previous
//
#include <hip/hip_runtime.h>

#define NB 8
#define NPTS 4160
#define NS 1024
#define KS 32
#define NROWS (NB*NS*KS)   /* 262144 */
#define R2 0.25f

__device__ __forceinline__ float fmul_(float a, float b){ return __fmul_rn(a,b); }
__device__ __forceinline__ float fadd_(float a, float b){ return __fadd_rn(a,b); }

// ---------------- init: zero stats region ----------------
__global__ void k_init(float* stats) {
  stats[threadIdx.x] = 0.f;
}

// DPP-based argmax step (max value, smallest index on ties).
// Robust to either bound_ctrl semantic: identity old = (-1.0f, INT_MAX) never
// wins (values are >= 0); a 0-fill would inject (0.0, 0) which also never wins
// for random continuous data (wave max > 0).
template<int CTRL>
__device__ __forceinline__ void amax_dpp(float& v, int& i) {
  int sv = __builtin_amdgcn_update_dpp((int)0xBF800000, __float_as_int(v), CTRL, 0xF, 0xF, false);
  int si = __builtin_amdgcn_update_dpp(0x7FFFFFFF, i, CTRL, 0xF, 0xF, false);
  float fv = __int_as_float(sv);
  if (fv > v || (fv == v && si < i)) { v = fv; i = si; }
}

// ---------------- FPS: one block per batch, 1 barrier/iter ----------------
__global__ __launch_bounds__(1024) void k_fps(const float* __restrict__ xyz,
                                              float* __restrict__ out_nx) {
  __shared__ float xs[NPTS], ys[NPTS], zs[NPTS];      // 49.9 KB
  __shared__ unsigned long long s_key[NS];            // 8 KB, per-iter slots
  int b = blockIdx.x;
  int tid = threadIdx.x;
  const float* X = xyz + (size_t)b*NPTS*3;
  for (int i = tid; i < NPTS; i += 1024) {
    xs[i] = X[3*i]; ys[i] = X[3*i+1]; zs[i] = X[3*i+2];
  }
  for (int i = tid; i < NS; i += 1024) s_key[i] = 0ull;
  float px[5], py[5], pz[5], dmin[5];
#pragma unroll
  for (int k = 0; k < 5; ++k) {
    int idx = tid + (k<<10);
    if (k < 4 || tid < (NPTS - 4096)) {
      px[k] = X[3*idx]; py[k] = X[3*idx+1]; pz[k] = X[3*idx+2];
      dmin[k] = 1e10f;
    } else { px[k]=0.f; py[k]=0.f; pz[k]=0.f; dmin[k] = -1.f; }
  }
  if (tid == 0) {
    out_nx[(size_t)b*NS*3]   = X[0];
    out_nx[(size_t)b*NS*3+1] = X[1];
    out_nx[(size_t)b*NS*3+2] = X[2];
  }
  int widx = 0;
  __syncthreads();
  for (int it = 1; it < NS; ++it) {
    float cx = xs[widx], cy = ys[widx], cz = zs[widx];
    float best = -1.f; int bi = 0x7fffffff;
#pragma unroll
    for (int k = 0; k < 5; ++k) {
      if (k < 4 || tid < (NPTS - 4096)) {
        float dx = px[k]-cx, dy = py[k]-cy, dz = pz[k]-cz;
        float d = fadd_(fadd_(fmul_(dx,dx), fmul_(dy,dy)), fmul_(dz,dz));
        float dm = fminf(dmin[k], d);
        dmin[k] = dm;
        if (dm > best) { best = dm; bi = tid + (k<<10); }
      }
    }
    // 64-lane argmax, result lands in lane 63 of each wave
    amax_dpp<0x111>(best, bi);   // row_shr:1
    amax_dpp<0x112>(best, bi);   // row_shr:2
    amax_dpp<0x114>(best, bi);   // row_shr:4
    amax_dpp<0x118>(best, bi);   // row_shr:8
    amax_dpp<0x142>(best, bi);   // row_bcast:15
    amax_dpp<0x143>(best, bi);   // row_bcast:31
    if ((tid & 63) == 63) {
      unsigned long long key = ((unsigned long long)__float_as_uint(best) << 32)
                             | (unsigned long long)(unsigned)(~(unsigned)bi);
      atomicMax(&s_key[it], key);
    }
    __syncthreads();
    unsigned long long kk = s_key[it];
    widx = (int)(~(unsigned)kk);
    if (tid == 0) {
      size_t o = (size_t)b*NS*3 + (size_t)it*3;
      out_nx[o] = xs[widx]; out_nx[o+1] = ys[widx]; out_nx[o+2] = zs[widx];
    }
  }
}

// ---------------- ball query: one wave per query, radius-gated ----------------
__global__ __launch_bounds__(256) void k_query(const float* __restrict__ xyz,
    const float* __restrict__ nx, int* __restrict__ gidx) {
  int gt = blockIdx.x*256 + threadIdx.x;
  int gw = gt >> 6;
  int lane = threadIdx.x & 63;
  int b = gw >> 10;
  const float* X = xyz + (size_t)b*NPTS*3;
  float qx = nx[(size_t)gw*3], qy = nx[(size_t)gw*3+1], qz = nx[(size_t)gw*3+2];
  float qsq = fadd_(fadd_(fmul_(qx,qx), fmul_(qy,qy)), fmul_(qz,qz));
  // sorted list in lanes 0..31; sentinel (R2, INT_MAX) radius-gates insertion
  float ld = R2; int li = 0x7fffffff;
  float mind = 3.3e38f; int mini = 0x7fffffff;   // global argmin (i0) tracker
  for (int c0 = 0; c0 < NPTS; c0 += 64) {
    int p = c0 + lane;
    float d = 3.3e38f; int pi = 0x7fffffff;
    if (p < NPTS) {
      float x = X[p*3], yv = X[p*3+1], z = X[p*3+2];
      float psq = fadd_(fadd_(fmul_(x,x), fmul_(yv,yv)), fmul_(z,z));
      float dot = fadd_(fadd_(fmul_(x,qx), fmul_(yv,qy)), fmul_(z,qz));
      d = fadd_(fadd_(fmul_(-2.f,dot), qsq), psq);
      pi = p;
    }
    if (d < mind || (d == mind && pi < mini)) { mind = d; mini = pi; }
    float c31d = __shfl(ld, 31); int c31i = __shfl(li, 31);
    bool candp = (d < c31d) || (d == c31d && pi < c31i);
    unsigned long long bm = __ballot(candp);
    while (bm) {
      int src = __builtin_ctzll(bm);
      bm &= bm - 1;
      float cd = __shfl(d, src);
      int   ci = __shfl(pi, src);
      bool lt = (cd < ld) || (cd == ld && ci < li);
      unsigned long long im = __ballot(lt) & 0xffffffffull;
      float sd = __shfl_up(ld, 1);
      int   si = __shfl_up(li, 1);
      if (im) {
        int pos = __builtin_ctzll(im);
        if (lane < 32 && lt) {
          ld = (lane == pos) ? cd : sd;
          li = (lane == pos) ? ci : si;
        }
      }
    }
  }
#pragma unroll
  for (int off = 32; off >= 1; off >>= 1) {
    float ov = __shfl_down(mind, off);
    int   oi = __shfl_down(mini, off);
    if (ov < mind || (ov == mind && oi < mini)) { mind = ov; mini = oi; }
  }
  int i0 = __shfl(mini, 0);
  if (lane < KS) {
    gidx[(size_t)gw*KS + lane] = (li == 0x7fffffff) ? i0 : li;
  }
}

// ---------------- pointwise-conv helpers ----------------
__device__ __forceinline__ void doc(float* acc, const float4* sW4, int c, float rc) {
#pragma unroll
  for (int o4 = 0; o4 < 16; ++o4) {
    float4 w = sW4[c*16 + o4];
    acc[o4*4]   = fmaf(rc, w.x, acc[o4*4]);
    acc[o4*4+1] = fmaf(rc, w.y, acc[o4*4+1]);
    acc[o4*4+2] = fmaf(rc, w.z, acc[o4*4+2]);
    acc[o4*4+3] = fmaf(rc, w.w, acc[o4*4+3]);
  }
}

__device__ __forceinline__ void doc2(float* a, const float4* sW4, int c, int o0, float rc) {
  float4 w0 = sW4[c*32 + (o0>>2)];
  float4 w1 = sW4[c*32 + (o0>>2) + 1];
  a[0]=fmaf(rc,w0.x,a[0]); a[1]=fmaf(rc,w0.y,a[1]); a[2]=fmaf(rc,w0.z,a[2]); a[3]=fmaf(rc,w0.w,a[3]);
  a[4]=fmaf(rc,w1.x,a[4]); a[5]=fmaf(rc,w1.y,a[5]); a[6]=fmaf(rc,w1.z,a[6]); a[7]=fmaf(rc,w1.w,a[7]);
}

// ---------------- layer 0: gather + conv(67->64) + stats ----------------
__global__ __launch_bounds__(256) void k_layer0(
    const float* __restrict__ xyz, const float* __restrict__ pts,
    const float* __restrict__ nx, const int* __restrict__ gidx,
    const float* __restrict__ W, const float* __restrict__ bias,
    float* __restrict__ y, float* __restrict__ stats) {
  __shared__ float4 sW4[67*16];
  __shared__ float sB[64];
  __shared__ float sStat[128];
  float* sW = (float*)sW4;
  int tid = threadIdx.x;
  for (int i = tid; i < 67*64; i += 256) {
    int c = i >> 6, o = i & 63;
    sW[i] = W[o*67 + c];
  }
  if (tid < 64) sB[tid] = bias[tid];
  if (tid < 128) sStat[tid] = 0.f;
  __syncthreads();
  int row = blockIdx.x*256 + tid;
  int b = row >> 15;
  int j = gidx[row];
  size_t q = (size_t)(row >> 5);
  float qx = nx[q*3], qy = nx[q*3+1], qz = nx[q*3+2];
  size_t pb = (size_t)b*NPTS + j;
  float acc[64];
#pragma unroll
  for (int o = 0; o < 64; ++o) acc[o] = sB[o];
  {
    float r0 = xyz[pb*3]   - qx;
    float r1 = xyz[pb*3+1] - qy;
    float r2 = xyz[pb*3+2] - qz;
    doc(acc, sW4, 0, r0); doc(acc, sW4, 1, r1); doc(acc, sW4, 2, r2);
  }
  const float4* P4 = (const float4*)(pts + pb*64);
  for (int c4 = 0; c4 < 16; ++c4) {
    float4 v = P4[c4];
    int c = 3 + c4*4;
    doc(acc, sW4, c, v.x); doc(acc, sW4, c+1, v.y);
    doc(acc, sW4, c+2, v.z); doc(acc, sW4, c+3, v.w);
  }
  float4* Y4 = (float4*)(y + (size_t)row*64);
#pragma unroll
  for (int o4 = 0; o4 < 16; ++o4)
    Y4[o4] = make_float4(acc[o4*4], acc[o4*4+1], acc[o4*4+2], acc[o4*4+3]);
#pragma unroll
  for (int o = 0; o < 64; ++o) {
    atomicAdd(&sStat[o], acc[o]);
    atomicAdd(&sStat[64+o], fmul_(acc[o],acc[o]));
  }
  __syncthreads();
  if (tid < 128) atomicAdd(&stats[tid], sStat[tid]);
}

// ---------------- layer 1: BN+relu + conv(64->64) in-place + stats ----------------
__global__ __launch_bounds__(256) void k_layer1(
    float* __restrict__ y, const float* __restrict__ W,
    const float* __restrict__ bias, float* stats) {
  __shared__ float4 sW4[64*16];
  __shared__ float sB[64], sSc[64], sSh[64];
  __shared__ float sStat[128];
  float* sW = (float*)sW4;
  int tid = threadIdx.x;
  for (int i = tid; i < 64*64; i += 256) {
    int c = i >> 6, o = i & 63;
    sW[i] = W[o*64 + c];
  }
  if (tid < 64) { sB[tid]=bias[tid]; sSc[tid]=stats[512+tid]; sSh[tid]=stats[576+tid]; }
  if (tid < 128) sStat[tid] = 0.f;
  __syncthreads();
  int row = blockIdx.x*256 + tid;
  float4* Y4 = (float4*)(y + (size_t)row*64);
  float acc[64];
#pragma unroll
  for (int o = 0; o < 64; ++o) acc[o] = sB[o];
  for (int c4 = 0; c4 < 16; ++c4) {
    float4 v = Y4[c4];
    int c = c4*4;
    doc(acc, sW4, c,   fmaxf(fmaf(v.x, sSc[c],   sSh[c]),   0.f));
    doc(acc, sW4, c+1, fmaxf(fmaf(v.y, sSc[c+1], sSh[c+1]), 0.f));
    doc(acc, sW4, c+2, fmaxf(fmaf(v.z, sSc[c+2], sSh[c+2]), 0.f));
    doc(acc, sW4, c+3, fmaxf(fmaf(v.w, sSc[c+3], sSh[c+3]), 0.f));
  }
#pragma unroll
  for (int o4 = 0; o4 < 16; ++o4)
    Y4[o4] = make_float4(acc[o4*4], acc[o4*4+1], acc[o4*4+2], acc[o4*4+3]);
#pragma unroll
  for (int o = 0; o < 64; ++o) {
    atomicAdd(&sStat[o], acc[o]);
    atomicAdd(&sStat[64+o], fmul_(acc[o],acc[o]));
  }
  __syncthreads();
  if (tid < 128) atomicAdd(&stats[128+tid], sStat[tid]);
}

// ---------------- layer 2: BN+relu + conv(64->128) + stats + max/min pool ----------------
__global__ __launch_bounds__(256) void k_layer2(
    const float* __restrict__ y, const float* __restrict__ W,
    const float* __restrict__ bias, float* stats,
    float* __restrict__ pmax, float* __restrict__ pmin) {
  __shared__ float4 sW4[64*32];
  __shared__ float sB[128], sSc[64], sSh[64];
  __shared__ float sStat[256];
  float* sW = (float*)sW4;
  int tid = threadIdx.x;
  for (int i = tid; i < 64*128; i += 256) {
    int c = i >> 7, o = i & 127;
    sW[i] = W[o*64 + c];
  }
  if (tid < 128) sB[tid] = bias[tid];
  if (tid < 64) { sSc[tid] = stats[640+tid]; sSh[tid] = stats[704+tid]; }
  sStat[tid] = 0.f;
  __syncthreads();
  int t = blockIdx.x*256 + tid;
  int g = t >> 4;
  int o0 = (t & 15) * 8;
  float mx[8], mn[8], sm[8], sq[8];
#pragma unroll
  for (int i=0;i<8;++i){ mx[i]=-3.4e38f; mn[i]=3.4e38f; sm[i]=0.f; sq[i]=0.f; }
  const float4* Y4 = (const float4*)(y) + (size_t)g*32*16;
  for (int n = 0; n < 32; ++n) {
    float a[8];
#pragma unroll
    for (int i=0;i<8;++i) a[i] = sB[o0+i];
    for (int c4 = 0; c4 < 16; ++c4) {
      float4 v = Y4[n*16 + c4];
      int c = c4*4;
      doc2(a, sW4, c,   o0, fmaxf(fmaf(v.x, sSc[c],   sSh[c]),   0.f));
      doc2(a, sW4, c+1, o0, fmaxf(fmaf(v.y, sSc[c+1], sSh[c+1]), 0.f));
      doc2(a, sW4, c+2, o0, fmaxf(fmaf(v.z, sSc[c+2], sSh[c+2]), 0.f));
      doc2(a, sW4, c+3, o0, fmaxf(fmaf(v.w, sSc[c+3], sSh[c+3]), 0.f));
    }
#pragma unroll
    for (int i=0;i<8;++i) {
      mx[i]=fmaxf(mx[i],a[i]); mn[i]=fminf(mn[i],a[i]);
      sm[i]=fadd_(sm[i],a[i]); sq[i]=fmaf(a[i],a[i],sq[i]);
    }
  }
  size_t ob = (size_t)g*128 + o0;
#pragma unroll
  for (int i=0;i<8;++i) { pmax[ob+i]=mx[i]; pmin[ob+i]=mn[i]; }
#pragma unroll
  for (int i=0;i<8;++i) {
    atomicAdd(&sStat[o0+i], sm[i]);
    atomicAdd(&sStat[128+o0+i], sq[i]);
  }
  __syncthreads();
  atomicAdd(&stats[256+tid], sStat[tid]);
}

// ---------------- BN finalize ----------------
__global__ void k_fin(float* stats, const float* g, const float* bb,
                      int cout, int soff, int ooff) {
  int o = threadIdx.x;
  if (o >= cout) return;
  float s = stats[soff + o], s2 = stats[soff + cout + o];
  float mean = s * (1.0f/262144.0f);
  float var = fmaxf(s2 * (1.0f/262144.0f) - mean*mean, 0.f);
  float sc = g[o] / sqrtf(var + 1e-5f);
  stats[ooff + o] = sc;
  stats[ooff + cout + o] = bb[o] - mean * sc;
}

// ---------------- output: BN+relu on pooled ----------------
__global__ __launch_bounds__(256) void k_out(const float* __restrict__ pmax,
    const float* __restrict__ pmin, const float* __restrict__ stats,
    float* __restrict__ outp) {
  int t = blockIdx.x*256 + threadIdx.x;
  int o = t & 127;
  float sc = stats[768+o], sh = stats[896+o];
  float sel = (sc >= 0.f) ? pmax[t] : pmin[t];
  outp[t] = fmaxf(fmaf(sel, sc, sh), 0.f);
}

extern "C" void kernel_launch(void* const* d_in, const int* in_sizes, int n_in,
                              void* d_out, int out_size, void* d_ws, size_t ws_size,
                              hipStream_t stream) {
  const float* xyz = (const float*)d_in[0];
  const float* pts = (const float*)d_in[1];
  const float* W0  = (const float*)d_in[2];
  const float* b0  = (const float*)d_in[3];
  const float* g0  = (const float*)d_in[4];
  const float* bb0 = (const float*)d_in[5];
  const float* W1  = (const float*)d_in[6];
  const float* b1  = (const float*)d_in[7];
  const float* g1  = (const float*)d_in[8];
  const float* bb1 = (const float*)d_in[9];
  const float* W2  = (const float*)d_in[10];
  const float* b2  = (const float*)d_in[11];
  const float* g2  = (const float*)d_in[12];
  const float* bb2 = (const float*)d_in[13];
  float* out_nx = (float*)d_out;
  float* out_np = out_nx + (size_t)NB*NS*3;
  float* ws = (float*)d_ws;
  float* stats = ws;                               // 1024 floats
  int* gidx = (int*)(ws + 1024);                   // NROWS ints
  float* ybuf = ws + 1024 + NROWS;                 // NROWS*64 floats
  float* pmax = ybuf + (size_t)NROWS*64;           // NB*NS*128
  float* pmin = pmax + (size_t)NB*NS*128;          // NB*NS*128

  k_init<<<1, 1024, 0, stream>>>(stats);
  k_fps<<<NB, 1024, 0, stream>>>(xyz, out_nx);
  k_query<<<2048, 256, 0, stream>>>(xyz, out_nx, gidx);
  k_layer0<<<1024, 256, 0, stream>>>(xyz, pts, out_nx, gidx, W0, b0, ybuf, stats);
  k_fin<<<1, 128, 0, stream>>>(stats, g0, bb0, 64, 0, 512);
  k_layer1<<<1024, 256, 0, stream>>>(ybuf, W1, b1, stats);
  k_fin<<<1, 128, 0, stream>>>(stats, g1, bb1, 64, 128, 640);
  k_layer2<<<512, 256, 0, stream>>>(ybuf, W2, b2, stats, pmax, pmin);
  k_fin<<<1, 128, 0, stream>>>(stats, g2, bb2, 128, 256, 768);
  k_out<<<4096, 256, 0, stream>>>(pmax, pmin, stats, out_np);
}

// Round 3
// 1700.779 us; speedup vs baseline: 1.6356x; 1.3924x over previous
//
#include <hip/hip_runtime.h>

#define NB 8
#define NPTS 4160
#define NS 1024
#define KS 32
#define NROWS (NB*NS*KS)   /* 262144 */
#define R2 0.25f

__device__ __forceinline__ float fmul_(float a, float b){ return __fmul_rn(a,b); }
__device__ __forceinline__ float fadd_(float a, float b){ return __fadd_rn(a,b); }

// ---------------- init: zero stats region ----------------
__global__ void k_init(float* stats) {
  stats[threadIdx.x] = 0.f;
}

// DPP-based argmax step (max value, smallest index on ties).
template<int CTRL>
__device__ __forceinline__ void amax_dpp(float& v, int& i) {
  int sv = __builtin_amdgcn_update_dpp((int)0xBF800000, __float_as_int(v), CTRL, 0xF, 0xF, false);
  int si = __builtin_amdgcn_update_dpp(0x7FFFFFFF, i, CTRL, 0xF, 0xF, false);
  float fv = __int_as_float(sv);
  if (fv > v || (fv == v && si < i)) { v = fv; i = si; }
}

// ---------------- FPS: one block per batch, 1 barrier/iter, all-register ----------------
__global__ __launch_bounds__(1024, 4) void k_fps(const float* __restrict__ xyz,
                                                 float* __restrict__ out_nx) {
  __shared__ float xs[NPTS], ys[NPTS], zs[NPTS];      // 49.9 KB
  __shared__ unsigned long long s_key[NS];            // 8 KB, per-iter slots
  int b = blockIdx.x;
  int tid = threadIdx.x;
  const float* X = xyz + (size_t)b*NPTS*3;
  for (int i = tid; i < NPTS; i += 1024) {
    xs[i] = X[3*i]; ys[i] = X[3*i+1]; zs[i] = X[3*i+2];
  }
  for (int i = tid; i < NS; i += 1024) s_key[i] = 0ull;
  // named scalars -> guaranteed register residency (no runtime-indexed arrays)
  float p0x = X[3*tid],          p0y = X[3*tid+1],          p0z = X[3*tid+2],          d0 = 1e10f;
  float p1x = X[3*(tid+1024)],   p1y = X[3*(tid+1024)+1],   p1z = X[3*(tid+1024)+2],   d1 = 1e10f;
  float p2x = X[3*(tid+2048)],   p2y = X[3*(tid+2048)+1],   p2z = X[3*(tid+2048)+2],   d2 = 1e10f;
  float p3x = X[3*(tid+3072)],   p3y = X[3*(tid+3072)+1],   p3z = X[3*(tid+3072)+2],   d3 = 1e10f;
  float p4x = 0.f, p4y = 0.f, p4z = 0.f, d4 = 1e10f;
  if (tid < 64) {                      // tail points 4096..4159, wave 0 only
    int i = 4096 + tid;
    p4x = X[3*i]; p4y = X[3*i+1]; p4z = X[3*i+2];
  }
  if (tid == 0) {
    out_nx[(size_t)b*NS*3]   = X[0];
    out_nx[(size_t)b*NS*3+1] = X[1];
    out_nx[(size_t)b*NS*3+2] = X[2];
  }
  int widx = 0;
  __syncthreads();
  for (int it = 1; it < NS; ++it) {
    float cx = xs[widx], cy = ys[widx], cz = zs[widx];
    float best; int bi;
    {
      float dx = p0x-cx, dy = p0y-cy, dz = p0z-cz;
      float d = fadd_(fadd_(fmul_(dx,dx), fmul_(dy,dy)), fmul_(dz,dz));
      d0 = fminf(d0, d); best = d0; bi = tid;
    }
    {
      float dx = p1x-cx, dy = p1y-cy, dz = p1z-cz;
      float d = fadd_(fadd_(fmul_(dx,dx), fmul_(dy,dy)), fmul_(dz,dz));
      d1 = fminf(d1, d);
      if (d1 > best) { best = d1; bi = tid + 1024; }
    }
    {
      float dx = p2x-cx, dy = p2y-cy, dz = p2z-cz;
      float d = fadd_(fadd_(fmul_(dx,dx), fmul_(dy,dy)), fmul_(dz,dz));
      d2 = fminf(d2, d);
      if (d2 > best) { best = d2; bi = tid + 2048; }
    }
    {
      float dx = p3x-cx, dy = p3y-cy, dz = p3z-cz;
      float d = fadd_(fadd_(fmul_(dx,dx), fmul_(dy,dy)), fmul_(dz,dz));
      d3 = fminf(d3, d);
      if (d3 > best) { best = d3; bi = tid + 3072; }
    }
    if (tid < 64) {                    // uniform branch: only wave 0 enters
      float dx = p4x-cx, dy = p4y-cy, dz = p4z-cz;
      float d = fadd_(fadd_(fmul_(dx,dx), fmul_(dy,dy)), fmul_(dz,dz));
      d4 = fminf(d4, d);
      if (d4 > best) { best = d4; bi = tid + 4096; }
    }
    // 64-lane argmax, result lands in lane 63 of each wave
    amax_dpp<0x111>(best, bi);   // row_shr:1
    amax_dpp<0x112>(best, bi);   // row_shr:2
    amax_dpp<0x114>(best, bi);   // row_shr:4
    amax_dpp<0x118>(best, bi);   // row_shr:8
    amax_dpp<0x142>(best, bi);   // row_bcast:15
    amax_dpp<0x143>(best, bi);   // row_bcast:31
    if ((tid & 63) == 63) {
      unsigned long long key = ((unsigned long long)__float_as_uint(best) << 32)
                             | (unsigned long long)(unsigned)(~(unsigned)bi);
      atomicMax(&s_key[it], key);
    }
    __syncthreads();
    unsigned long long kk = s_key[it];
    widx = (int)(~(unsigned)kk);
    if (tid == 0) {
      size_t o = (size_t)b*NS*3 + (size_t)it*3;
      out_nx[o] = xs[widx]; out_nx[o+1] = ys[widx]; out_nx[o+2] = zs[widx];
    }
  }
}

// ---------------- ball query: one wave per query, radius-gated ----------------
__global__ __launch_bounds__(256) void k_query(const float* __restrict__ xyz,
    const float* __restrict__ nx, int* __restrict__ gidx) {
  int gt = blockIdx.x*256 + threadIdx.x;
  int gw = gt >> 6;
  int lane = threadIdx.x & 63;
  int b = gw >> 10;
  const float* X = xyz + (size_t)b*NPTS*3;
  float qx = nx[(size_t)gw*3], qy = nx[(size_t)gw*3+1], qz = nx[(size_t)gw*3+2];
  float qsq = fadd_(fadd_(fmul_(qx,qx), fmul_(qy,qy)), fmul_(qz,qz));
  float ld = R2; int li = 0x7fffffff;
  float mind = 3.3e38f; int mini = 0x7fffffff;
  for (int c0 = 0; c0 < NPTS; c0 += 64) {
    int p = c0 + lane;
    float d = 3.3e38f; int pi = 0x7fffffff;
    if (p < NPTS) {
      float x = X[p*3], yv = X[p*3+1], z = X[p*3+2];
      float psq = fadd_(fadd_(fmul_(x,x), fmul_(yv,yv)), fmul_(z,z));
      float dot = fadd_(fadd_(fmul_(x,qx), fmul_(yv,qy)), fmul_(z,qz));
      d = fadd_(fadd_(fmul_(-2.f,dot), qsq), psq);
      pi = p;
    }
    if (d < mind || (d == mind && pi < mini)) { mind = d; mini = pi; }
    float c31d = __shfl(ld, 31); int c31i = __shfl(li, 31);
    bool candp = (d < c31d) || (d == c31d && pi < c31i);
    unsigned long long bm = __ballot(candp);
    while (bm) {
      int src = __builtin_ctzll(bm);
      bm &= bm - 1;
      float cd = __shfl(d, src);
      int   ci = __shfl(pi, src);
      bool lt = (cd < ld) || (cd == ld && ci < li);
      unsigned long long im = __ballot(lt) & 0xffffffffull;
      float sd = __shfl_up(ld, 1);
      int   si = __shfl_up(li, 1);
      if (im) {
        int pos = __builtin_ctzll(im);
        if (lane < 32 && lt) {
          ld = (lane == pos) ? cd : sd;
          li = (lane == pos) ? ci : si;
        }
      }
    }
  }
#pragma unroll
  for (int off = 32; off >= 1; off >>= 1) {
    float ov = __shfl_down(mind, off);
    int   oi = __shfl_down(mini, off);
    if (ov < mind || (ov == mind && oi < mini)) { mind = ov; mini = oi; }
  }
  int i0 = __shfl(mini, 0);
  if (lane < KS) {
    gidx[(size_t)gw*KS + lane] = (li == 0x7fffffff) ? i0 : li;
  }
}

// ---------------- pointwise-conv helper ----------------
__device__ __forceinline__ void doc(float* acc, const float4* sW4, int c, float rc) {
#pragma unroll
  for (int o4 = 0; o4 < 16; ++o4) {
    float4 w = sW4[c*16 + o4];
    acc[o4*4]   = fmaf(rc, w.x, acc[o4*4]);
    acc[o4*4+1] = fmaf(rc, w.y, acc[o4*4+1]);
    acc[o4*4+2] = fmaf(rc, w.z, acc[o4*4+2]);
    acc[o4*4+3] = fmaf(rc, w.w, acc[o4*4+3]);
  }
}

// Per-wave 64-channel (sum, sumsq) reduction via LDS transpose.
// Private per-wave tile -> no extra block barriers; replaces 128 same-address
// LDS atomics (64-way serialized RMW) per thread with ~128 conflict-free LDS ops.
__device__ __forceinline__ void wave_stats64(const float* acc, float* sStat, int tid) {
  __shared__ float sTr[4][64][17];
  int wid = tid >> 6, l = tid & 63;
  int rq = (l >> 4) * 16;          // row-quarter start
  int ch = l & 15;
#pragma unroll
  for (int pass = 0; pass < 4; ++pass) {
    int c0 = pass * 16;
#pragma unroll
    for (int j = 0; j < 16; ++j)
      sTr[wid][l][j] = acc[c0 + j];
    float s = 0.f, q = 0.f;
#pragma unroll
    for (int k = 0; k < 16; ++k) {
      float v = sTr[wid][rq + k][ch];
      s += v; q = fmaf(v, v, q);
    }
    s += __shfl_xor(s, 16); s += __shfl_xor(s, 32);
    q += __shfl_xor(q, 16); q += __shfl_xor(q, 32);
    if (l < 16) {
      atomicAdd(&sStat[c0 + ch], s);
      atomicAdd(&sStat[64 + c0 + ch], q);
    }
  }
}

// ---------------- layer 0: gather + conv(67->64) + stats ----------------
__global__ __launch_bounds__(256) void k_layer0(
    const float* __restrict__ xyz, const float* __restrict__ pts,
    const float* __restrict__ nx, const int* __restrict__ gidx,
    const float* __restrict__ W, const float* __restrict__ bias,
    float* __restrict__ y, float* __restrict__ stats) {
  __shared__ float4 sW4[67*16];
  __shared__ float sB[64];
  __shared__ float sStat[128];
  float* sW = (float*)sW4;
  int tid = threadIdx.x;
  for (int i = tid; i < 67*64; i += 256) {
    int c = i >> 6, o = i & 63;
    sW[i] = W[o*67 + c];
  }
  if (tid < 64) sB[tid] = bias[tid];
  if (tid < 128) sStat[tid] = 0.f;
  __syncthreads();
  int row = blockIdx.x*256 + tid;
  int b = row >> 15;
  int j = gidx[row];
  size_t q = (size_t)(row >> 5);
  float qx = nx[q*3], qy = nx[q*3+1], qz = nx[q*3+2];
  size_t pb = (size_t)b*NPTS + j;
  float acc[64];
#pragma unroll
  for (int o = 0; o < 64; ++o) acc[o] = sB[o];
  {
    float r0 = xyz[pb*3]   - qx;
    float r1 = xyz[pb*3+1] - qy;
    float r2 = xyz[pb*3+2] - qz;
    doc(acc, sW4, 0, r0); doc(acc, sW4, 1, r1); doc(acc, sW4, 2, r2);
  }
  const float4* P4 = (const float4*)(pts + pb*64);
  for (int c4 = 0; c4 < 16; ++c4) {
    float4 v = P4[c4];
    int c = 3 + c4*4;
    doc(acc, sW4, c, v.x); doc(acc, sW4, c+1, v.y);
    doc(acc, sW4, c+2, v.z); doc(acc, sW4, c+3, v.w);
  }
  float4* Y4 = (float4*)(y + (size_t)row*64);
#pragma unroll
  for (int o4 = 0; o4 < 16; ++o4)
    Y4[o4] = make_float4(acc[o4*4], acc[o4*4+1], acc[o4*4+2], acc[o4*4+3]);
  wave_stats64(acc, sStat, tid);
  __syncthreads();
  if (tid < 128) atomicAdd(&stats[tid], sStat[tid]);
}

// ---------------- layer 1: BN+relu + conv(64->64) in-place + stats ----------------
__global__ __launch_bounds__(256) void k_layer1(
    float* __restrict__ y, const float* __restrict__ W,
    const float* __restrict__ bias, float* stats) {
  __shared__ float4 sW4[64*16];
  __shared__ float sB[64], sSc[64], sSh[64];
  __shared__ float sStat[128];
  float* sW = (float*)sW4;
  int tid = threadIdx.x;
  for (int i = tid; i < 64*64; i += 256) {
    int c = i >> 6, o = i & 63;
    sW[i] = W[o*64 + c];
  }
  if (tid < 64) { sB[tid]=bias[tid]; sSc[tid]=stats[512+tid]; sSh[tid]=stats[576+tid]; }
  if (tid < 128) sStat[tid] = 0.f;
  __syncthreads();
  int row = blockIdx.x*256 + tid;
  float4* Y4 = (float4*)(y + (size_t)row*64);
  float acc[64];
#pragma unroll
  for (int o = 0; o < 64; ++o) acc[o] = sB[o];
  for (int c4 = 0; c4 < 16; ++c4) {
    float4 v = Y4[c4];
    int c = c4*4;
    doc(acc, sW4, c,   fmaxf(fmaf(v.x, sSc[c],   sSh[c]),   0.f));
    doc(acc, sW4, c+1, fmaxf(fmaf(v.y, sSc[c+1], sSh[c+1]), 0.f));
    doc(acc, sW4, c+2, fmaxf(fmaf(v.z, sSc[c+2], sSh[c+2]), 0.f));
    doc(acc, sW4, c+3, fmaxf(fmaf(v.w, sSc[c+3], sSh[c+3]), 0.f));
  }
#pragma unroll
  for (int o4 = 0; o4 < 16; ++o4)
    Y4[o4] = make_float4(acc[o4*4], acc[o4*4+1], acc[o4*4+2], acc[o4*4+3]);
  wave_stats64(acc, sStat, tid);
  __syncthreads();
  if (tid < 128) atomicAdd(&stats[128+tid], sStat[tid]);
}

// ---------------- layer 2: BN+relu + conv(64->128) + stats + max/min pool ----------------
__global__ __launch_bounds__(256) void k_layer2(
    const float* __restrict__ y, const float* __restrict__ W,
    const float* __restrict__ bias, float* stats,
    float* __restrict__ pmax, float* __restrict__ pmin) {
  __shared__ float4 sW4[64*32];
  __shared__ float sB[128], sSc[64], sSh[64];
  __shared__ float sStat[256];
  float* sW = (float*)sW4;
  int tid = threadIdx.x;
  for (int i = tid; i < 64*128; i += 256) {
    int c = i >> 7, o = i & 127;
    sW[i] = W[o*64 + c];
  }
  if (tid < 128) sB[tid] = bias[tid];
  if (tid < 64) { sSc[tid] = stats[640+tid]; sSh[tid] = stats[704+tid]; }
  sStat[tid] = 0.f;
  __syncthreads();
  int t = blockIdx.x*256 + tid;
  int g = t >> 4;
  int o0 = (t & 15) * 8;
  int w0i = o0 >> 2;
  float mx[8], mn[8], sm[8], sq[8];
#pragma unroll
  for (int i=0;i<8;++i){ mx[i]=-3.4e38f; mn[i]=3.4e38f; sm[i]=0.f; sq[i]=0.f; }
  const float4* Y4 = (const float4*)(y) + (size_t)g*32*16;
#pragma unroll 1
  for (int rb = 0; rb < 8; ++rb) {       // 4-row tiles: weights hoisted per c4
    float a[4][8];
#pragma unroll
    for (int j=0;j<4;++j)
#pragma unroll
      for (int i=0;i<8;++i) a[j][i] = sB[o0+i];
#pragma unroll
    for (int c4 = 0; c4 < 16; ++c4) {
      float4 w[8];
#pragma unroll
      for (int ch = 0; ch < 4; ++ch) {
        w[ch*2]   = sW4[(c4*4+ch)*32 + w0i];
        w[ch*2+1] = sW4[(c4*4+ch)*32 + w0i + 1];
      }
      float sc0=sSc[c4*4], sc1=sSc[c4*4+1], sc2=sSc[c4*4+2], sc3=sSc[c4*4+3];
      float sh0=sSh[c4*4], sh1=sSh[c4*4+1], sh2=sSh[c4*4+2], sh3=sSh[c4*4+3];
#pragma unroll
      for (int j = 0; j < 4; ++j) {
        float4 v = Y4[(rb*4+j)*16 + c4];
        float r0 = fmaxf(fmaf(v.x, sc0, sh0), 0.f);
        float r1 = fmaxf(fmaf(v.y, sc1, sh1), 0.f);
        float r2 = fmaxf(fmaf(v.z, sc2, sh2), 0.f);
        float r3 = fmaxf(fmaf(v.w, sc3, sh3), 0.f);
        a[j][0]=fmaf(r0,w[0].x,a[j][0]); a[j][1]=fmaf(r0,w[0].y,a[j][1]);
        a[j][2]=fmaf(r0,w[0].z,a[j][2]); a[j][3]=fmaf(r0,w[0].w,a[j][3]);
        a[j][4]=fmaf(r0,w[1].x,a[j][4]); a[j][5]=fmaf(r0,w[1].y,a[j][5]);
        a[j][6]=fmaf(r0,w[1].z,a[j][6]); a[j][7]=fmaf(r0,w[1].w,a[j][7]);
        a[j][0]=fmaf(r1,w[2].x,a[j][0]); a[j][1]=fmaf(r1,w[2].y,a[j][1]);
        a[j][2]=fmaf(r1,w[2].z,a[j][2]); a[j][3]=fmaf(r1,w[2].w,a[j][3]);
        a[j][4]=fmaf(r1,w[3].x,a[j][4]); a[j][5]=fmaf(r1,w[3].y,a[j][5]);
        a[j][6]=fmaf(r1,w[3].z,a[j][6]); a[j][7]=fmaf(r1,w[3].w,a[j][7]);
        a[j][0]=fmaf(r2,w[4].x,a[j][0]); a[j][1]=fmaf(r2,w[4].y,a[j][1]);
        a[j][2]=fmaf(r2,w[4].z,a[j][2]); a[j][3]=fmaf(r2,w[4].w,a[j][3]);
        a[j][4]=fmaf(r2,w[5].x,a[j][4]); a[j][5]=fmaf(r2,w[5].y,a[j][5]);
        a[j][6]=fmaf(r2,w[5].z,a[j][6]); a[j][7]=fmaf(r2,w[5].w,a[j][7]);
        a[j][0]=fmaf(r3,w[6].x,a[j][0]); a[j][1]=fmaf(r3,w[6].y,a[j][1]);
        a[j][2]=fmaf(r3,w[6].z,a[j][2]); a[j][3]=fmaf(r3,w[6].w,a[j][3]);
        a[j][4]=fmaf(r3,w[7].x,a[j][4]); a[j][5]=fmaf(r3,w[7].y,a[j][5]);
        a[j][6]=fmaf(r3,w[7].z,a[j][6]); a[j][7]=fmaf(r3,w[7].w,a[j][7]);
      }
    }
#pragma unroll
    for (int j = 0; j < 4; ++j)
#pragma unroll
      for (int i = 0; i < 8; ++i) {
        float av = a[j][i];
        mx[i]=fmaxf(mx[i],av); mn[i]=fminf(mn[i],av);
        sm[i]=fadd_(sm[i],av); sq[i]=fmaf(av,av,sq[i]);
      }
  }
  size_t ob = (size_t)g*128 + o0;
#pragma unroll
  for (int i=0;i<8;++i) { pmax[ob+i]=mx[i]; pmin[ob+i]=mn[i]; }
#pragma unroll
  for (int i=0;i<8;++i) {
    atomicAdd(&sStat[o0+i], sm[i]);
    atomicAdd(&sStat[128+o0+i], sq[i]);
  }
  __syncthreads();
  atomicAdd(&stats[256+tid], sStat[tid]);
}

// ---------------- BN finalize ----------------
__global__ void k_fin(float* stats, const float* g, const float* bb,
                      int cout, int soff, int ooff) {
  int o = threadIdx.x;
  if (o >= cout) return;
  float s = stats[soff + o], s2 = stats[soff + cout + o];
  float mean = s * (1.0f/262144.0f);
  float var = fmaxf(s2 * (1.0f/262144.0f) - mean*mean, 0.f);
  float sc = g[o] / sqrtf(var + 1e-5f);
  stats[ooff + o] = sc;
  stats[ooff + cout + o] = bb[o] - mean * sc;
}

// ---------------- output: BN+relu on pooled ----------------
__global__ __launch_bounds__(256) void k_out(const float* __restrict__ pmax,
    const float* __restrict__ pmin, const float* __restrict__ stats,
    float* __restrict__ outp) {
  int t = blockIdx.x*256 + threadIdx.x;
  int o = t & 127;
  float sc = stats[768+o], sh = stats[896+o];
  float sel = (sc >= 0.f) ? pmax[t] : pmin[t];
  outp[t] = fmaxf(fmaf(sel, sc, sh), 0.f);
}

extern "C" void kernel_launch(void* const* d_in, const int* in_sizes, int n_in,
                              void* d_out, int out_size, void* d_ws, size_t ws_size,
                              hipStream_t stream) {
  const float* xyz = (const float*)d_in[0];
  const float* pts = (const float*)d_in[1];
  const float* W0  = (const float*)d_in[2];
  const float* b0  = (const float*)d_in[3];
  const float* g0  = (const float*)d_in[4];
  const float* bb0 = (const float*)d_in[5];
  const float* W1  = (const float*)d_in[6];
  const float* b1  = (const float*)d_in[7];
  const float* g1  = (const float*)d_in[8];
  const float* bb1 = (const float*)d_in[9];
  const float* W2  = (const float*)d_in[10];
  const float* b2  = (const float*)d_in[11];
  const float* g2  = (const float*)d_in[12];
  const float* bb2 = (const float*)d_in[13];
  float* out_nx = (float*)d_out;
  float* out_np = out_nx + (size_t)NB*NS*3;
  float* ws = (float*)d_ws;
  float* stats = ws;                               // 1024 floats
  int* gidx = (int*)(ws + 1024);                   // NROWS ints
  float* ybuf = ws + 1024 + NROWS;                 // NROWS*64 floats
  float* pmax = ybuf + (size_t)NROWS*64;           // NB*NS*128
  float* pmin = pmax + (size_t)NB*NS*128;          // NB*NS*128

  k_init<<<1, 1024, 0, stream>>>(stats);
  k_fps<<<NB, 1024, 0, stream>>>(xyz, out_nx);
  k_query<<<2048, 256, 0, stream>>>(xyz, out_nx, gidx);
  k_layer0<<<1024, 256, 0, stream>>>(xyz, pts, out_nx, gidx, W0, b0, ybuf, stats);
  k_fin<<<1, 128, 0, stream>>>(stats, g0, bb0, 64, 0, 512);
  k_layer1<<<1024, 256, 0, stream>>>(ybuf, W1, b1, stats);
  k_fin<<<1, 128, 0, stream>>>(stats, g1, bb1, 64, 128, 640);
  k_layer2<<<512, 256, 0, stream>>>(ybuf, W2, b2, stats, pmax, pmin);
  k_fin<<<1, 128, 0, stream>>>(stats, g2, bb2, 128, 256, 768);
  k_out<<<4096, 256, 0, stream>>>(pmax, pmin, stats, out_np);
}

// Round 4
// 1531.840 us; speedup vs baseline: 1.8160x; 1.1103x over previous
//
#include <hip/hip_runtime.h>

#define NB 8
#define NPTS 4160
#define NS 1024
#define KS 32
#define NROWS (NB*NS*KS)   /* 262144 */
#define R2 0.25f

__device__ __forceinline__ float fmul_(float a, float b){ return __fmul_rn(a,b); }
__device__ __forceinline__ float fadd_(float a, float b){ return __fadd_rn(a,b); }

// ---------------- init: zero stats region ----------------
__global__ void k_init(float* stats) {
  stats[threadIdx.x] = 0.f;
}

// DPP-based argmax step (max value, smallest index on ties).
template<int CTRL>
__device__ __forceinline__ void amax_dpp(float& v, int& i) {
  int sv = __builtin_amdgcn_update_dpp((int)0xBF800000, __float_as_int(v), CTRL, 0xF, 0xF, false);
  int si = __builtin_amdgcn_update_dpp(0x7FFFFFFF, i, CTRL, 0xF, 0xF, false);
  float fv = __int_as_float(sv);
  if (fv > v || (fv == v && si < i)) { v = fv; i = si; }
}

// 64-bit (hi,lo) lexicographic max step via DPP; identity (0,0) never wins.
template<int CTRL>
__device__ __forceinline__ void umax64_dpp(unsigned& hi, unsigned& lo) {
  unsigned shi = (unsigned)__builtin_amdgcn_update_dpp(0, (int)hi, CTRL, 0xF, 0xF, false);
  unsigned slo = (unsigned)__builtin_amdgcn_update_dpp(0, (int)lo, CTRL, 0xF, 0xF, false);
  if (shi > hi || (shi == hi && slo > lo)) { hi = shi; lo = slo; }
}

// ---------------- FPS: one 256-thread block per batch ----------------
// 16 pts/thread + wave-0 tail, all coords pinned in VGPRs via asm (the
// compiler otherwise sinks the loads back into the loop -> L2 re-fetch
// every iteration; that was the 1080us plateau: VGPR_Count=20).
__global__ __launch_bounds__(256, 1) void k_fps(const float* __restrict__ xyz,
                                                float* __restrict__ out_nx) {
  __shared__ float xs[NPTS], ys[NPTS], zs[NPTS];      // 48.8 KB
  __shared__ unsigned long long s_slot[2][4];         // ping-pong wave keys
  int b = blockIdx.x;
  int tid = threadIdx.x;
  const float* X = xyz + (size_t)b*NPTS*3;
  for (int i = tid; i < NPTS; i += 256) {
    xs[i] = X[3*i]; ys[i] = X[3*i+1]; zs[i] = X[3*i+2];
  }
  float px[16], py[16], pz[16], dm[16];
#pragma unroll
  for (int k = 0; k < 16; ++k) {
    int i = tid + (k<<8);
    px[k] = X[3*i]; py[k] = X[3*i+1]; pz[k] = X[3*i+2]; dm[k] = 1e10f;
  }
  float tx = 0.f, ty = 0.f, tz = 0.f, tdm = 1e10f;
  if (tid < 64) {                       // tail points 4096..4159 (wave 0)
    int i = 4096 + tid;
    tx = X[3*i]; ty = X[3*i+1]; tz = X[3*i+2];
  }
  float cx = X[0], cy = X[1], cz = X[2];
  if (tid == 0) {
    out_nx[(size_t)b*NS*3]   = cx;
    out_nx[(size_t)b*NS*3+1] = cy;
    out_nx[(size_t)b*NS*3+2] = cz;
  }
  __syncthreads();
  for (int it = 1; it < NS; ++it) {
    // pin loop-carried state in VGPRs: asm "writes" them, so they cannot be
    // rematerialized from memory by the scheduler
#pragma unroll
    for (int k = 0; k < 16; ++k)
      asm volatile("" : "+v"(px[k]), "+v"(py[k]), "+v"(pz[k]), "+v"(dm[k]));
    asm volatile("" : "+v"(tx), "+v"(ty), "+v"(tz), "+v"(tdm));
    float best; int bi;
    {
      float dx = px[0]-cx, dy = py[0]-cy, dz = pz[0]-cz;
      float d = fadd_(fadd_(fmul_(dx,dx), fmul_(dy,dy)), fmul_(dz,dz));
      dm[0] = fminf(dm[0], d); best = dm[0]; bi = tid;
    }
#pragma unroll
    for (int k = 1; k < 16; ++k) {
      float dx = px[k]-cx, dy = py[k]-cy, dz = pz[k]-cz;
      float d = fadd_(fadd_(fmul_(dx,dx), fmul_(dy,dy)), fmul_(dz,dz));
      dm[k] = fminf(dm[k], d);
      if (dm[k] > best) { best = dm[k]; bi = tid + (k<<8); }
    }
    if (tid < 64) {                    // wave-uniform branch
      float dx = tx-cx, dy = ty-cy, dz = tz-cz;
      float d = fadd_(fadd_(fmul_(dx,dx), fmul_(dy,dy)), fmul_(dz,dz));
      tdm = fminf(tdm, d);
      if (tdm > best) { best = tdm; bi = 4096 + tid; }
    }
    // 64-lane argmax -> lane 63 of each wave
    amax_dpp<0x111>(best, bi);   // row_shr:1
    amax_dpp<0x112>(best, bi);   // row_shr:2
    amax_dpp<0x114>(best, bi);   // row_shr:4
    amax_dpp<0x118>(best, bi);   // row_shr:8
    amax_dpp<0x142>(best, bi);   // row_bcast:15
    amax_dpp<0x143>(best, bi);   // row_bcast:31
    if ((tid & 63) == 63) {
      s_slot[it & 1][tid >> 6] =
        ((unsigned long long)__float_as_uint(best) << 32)
        | (unsigned long long)(unsigned)(~(unsigned)bi);
    }
    __syncthreads();
    // 4-key lexicographic max in lanes 0..3 of every wave (2 DPP steps),
    // result in lane 3; broadcast via readlane.
    unsigned long long kk = s_slot[it & 1][tid & 3];
    unsigned khi = (unsigned)(kk >> 32), klo = (unsigned)kk;
    umax64_dpp<0x111>(khi, klo);
    umax64_dpp<0x112>(khi, klo);
    int widx = (int)~(unsigned)__builtin_amdgcn_readlane((int)klo, 3);
    cx = xs[widx]; cy = ys[widx]; cz = zs[widx];
    if (tid == 0) {
      size_t o = (size_t)b*NS*3 + (size_t)it*3;
      out_nx[o] = cx; out_nx[o+1] = cy; out_nx[o+2] = cz;
    }
  }
}

// ---------------- ball query: one wave per query, radius-gated ----------------
__global__ __launch_bounds__(256) void k_query(const float* __restrict__ xyz,
    const float* __restrict__ nx, int* __restrict__ gidx) {
  int gt = blockIdx.x*256 + threadIdx.x;
  int gw = gt >> 6;
  int lane = threadIdx.x & 63;
  int b = gw >> 10;
  const float* X = xyz + (size_t)b*NPTS*3;
  float qx = nx[(size_t)gw*3], qy = nx[(size_t)gw*3+1], qz = nx[(size_t)gw*3+2];
  float qsq = fadd_(fadd_(fmul_(qx,qx), fmul_(qy,qy)), fmul_(qz,qz));
  float ld = R2; int li = 0x7fffffff;
  float mind = 3.3e38f; int mini = 0x7fffffff;
  for (int c0 = 0; c0 < NPTS; c0 += 64) {
    int p = c0 + lane;
    float d = 3.3e38f; int pi = 0x7fffffff;
    if (p < NPTS) {
      float x = X[p*3], yv = X[p*3+1], z = X[p*3+2];
      float psq = fadd_(fadd_(fmul_(x,x), fmul_(yv,yv)), fmul_(z,z));
      float dot = fadd_(fadd_(fmul_(x,qx), fmul_(yv,qy)), fmul_(z,qz));
      d = fadd_(fadd_(fmul_(-2.f,dot), qsq), psq);
      pi = p;
    }
    if (d < mind || (d == mind && pi < mini)) { mind = d; mini = pi; }
    float c31d = __shfl(ld, 31); int c31i = __shfl(li, 31);
    bool candp = (d < c31d) || (d == c31d && pi < c31i);
    unsigned long long bm = __ballot(candp);
    while (bm) {
      int src = __builtin_ctzll(bm);
      bm &= bm - 1;
      float cd = __shfl(d, src);
      int   ci = __shfl(pi, src);
      bool lt = (cd < ld) || (cd == ld && ci < li);
      unsigned long long im = __ballot(lt) & 0xffffffffull;
      float sd = __shfl_up(ld, 1);
      int   si = __shfl_up(li, 1);
      if (im) {
        int pos = __builtin_ctzll(im);
        if (lane < 32 && lt) {
          ld = (lane == pos) ? cd : sd;
          li = (lane == pos) ? ci : si;
        }
      }
    }
  }
#pragma unroll
  for (int off = 32; off >= 1; off >>= 1) {
    float ov = __shfl_down(mind, off);
    int   oi = __shfl_down(mini, off);
    if (ov < mind || (ov == mind && oi < mini)) { mind = ov; mini = oi; }
  }
  int i0 = __shfl(mini, 0);
  if (lane < KS) {
    gidx[(size_t)gw*KS + lane] = (li == 0x7fffffff) ? i0 : li;
  }
}

// ---------------- pointwise-conv helper ----------------
__device__ __forceinline__ void doc(float* acc, const float4* sW4, int c, float rc) {
#pragma unroll
  for (int o4 = 0; o4 < 16; ++o4) {
    float4 w = sW4[c*16 + o4];
    acc[o4*4]   = fmaf(rc, w.x, acc[o4*4]);
    acc[o4*4+1] = fmaf(rc, w.y, acc[o4*4+1]);
    acc[o4*4+2] = fmaf(rc, w.z, acc[o4*4+2]);
    acc[o4*4+3] = fmaf(rc, w.w, acc[o4*4+3]);
  }
}

// Per-wave 64-channel (sum, sumsq) reduction via LDS transpose.
__device__ __forceinline__ void wave_stats64(const float* acc, float* sStat, int tid) {
  __shared__ float sTr[4][64][17];
  int wid = tid >> 6, l = tid & 63;
  int rq = (l >> 4) * 16;
  int ch = l & 15;
#pragma unroll
  for (int pass = 0; pass < 4; ++pass) {
    int c0 = pass * 16;
#pragma unroll
    for (int j = 0; j < 16; ++j)
      sTr[wid][l][j] = acc[c0 + j];
    float s = 0.f, q = 0.f;
#pragma unroll
    for (int k = 0; k < 16; ++k) {
      float v = sTr[wid][rq + k][ch];
      s += v; q = fmaf(v, v, q);
    }
    s += __shfl_xor(s, 16); s += __shfl_xor(s, 32);
    q += __shfl_xor(q, 16); q += __shfl_xor(q, 32);
    if (l < 16) {
      atomicAdd(&sStat[c0 + ch], s);
      atomicAdd(&sStat[64 + c0 + ch], q);
    }
  }
}

// ---------------- layer 0: gather + conv(67->64) + stats ----------------
__global__ __launch_bounds__(256) void k_layer0(
    const float* __restrict__ xyz, const float* __restrict__ pts,
    const float* __restrict__ nx, const int* __restrict__ gidx,
    const float* __restrict__ W, const float* __restrict__ bias,
    float* __restrict__ y, float* __restrict__ stats) {
  __shared__ float4 sW4[67*16];
  __shared__ float sB[64];
  __shared__ float sStat[128];
  float* sW = (float*)sW4;
  int tid = threadIdx.x;
  for (int i = tid; i < 67*64; i += 256) {
    int c = i >> 6, o = i & 63;
    sW[i] = W[o*67 + c];
  }
  if (tid < 64) sB[tid] = bias[tid];
  if (tid < 128) sStat[tid] = 0.f;
  __syncthreads();
  int row = blockIdx.x*256 + tid;
  int b = row >> 15;
  int j = gidx[row];
  size_t q = (size_t)(row >> 5);
  float qx = nx[q*3], qy = nx[q*3+1], qz = nx[q*3+2];
  size_t pb = (size_t)b*NPTS + j;
  float acc[64];
#pragma unroll
  for (int o = 0; o < 64; ++o) acc[o] = sB[o];
  {
    float r0 = xyz[pb*3]   - qx;
    float r1 = xyz[pb*3+1] - qy;
    float r2 = xyz[pb*3+2] - qz;
    doc(acc, sW4, 0, r0); doc(acc, sW4, 1, r1); doc(acc, sW4, 2, r2);
  }
  const float4* P4 = (const float4*)(pts + pb*64);
  for (int c4 = 0; c4 < 16; ++c4) {
    float4 v = P4[c4];
    int c = 3 + c4*4;
    doc(acc, sW4, c, v.x); doc(acc, sW4, c+1, v.y);
    doc(acc, sW4, c+2, v.z); doc(acc, sW4, c+3, v.w);
  }
  float4* Y4 = (float4*)(y + (size_t)row*64);
#pragma unroll
  for (int o4 = 0; o4 < 16; ++o4)
    Y4[o4] = make_float4(acc[o4*4], acc[o4*4+1], acc[o4*4+2], acc[o4*4+3]);
  wave_stats64(acc, sStat, tid);
  __syncthreads();
  if (tid < 128) atomicAdd(&stats[tid], sStat[tid]);
}

// ---------------- layer 1: BN+relu + conv(64->64) in-place + stats ----------------
__global__ __launch_bounds__(256) void k_layer1(
    float* __restrict__ y, const float* __restrict__ W,
    const float* __restrict__ bias, float* stats) {
  __shared__ float4 sW4[64*16];
  __shared__ float sB[64], sSc[64], sSh[64];
  __shared__ float sStat[128];
  float* sW = (float*)sW4;
  int tid = threadIdx.x;
  for (int i = tid; i < 64*64; i += 256) {
    int c = i >> 6, o = i & 63;
    sW[i] = W[o*64 + c];
  }
  if (tid < 64) { sB[tid]=bias[tid]; sSc[tid]=stats[512+tid]; sSh[tid]=stats[576+tid]; }
  if (tid < 128) sStat[tid] = 0.f;
  __syncthreads();
  int row = blockIdx.x*256 + tid;
  float4* Y4 = (float4*)(y + (size_t)row*64);
  float acc[64];
#pragma unroll
  for (int o = 0; o < 64; ++o) acc[o] = sB[o];
  for (int c4 = 0; c4 < 16; ++c4) {
    float4 v = Y4[c4];
    int c = c4*4;
    doc(acc, sW4, c,   fmaxf(fmaf(v.x, sSc[c],   sSh[c]),   0.f));
    doc(acc, sW4, c+1, fmaxf(fmaf(v.y, sSc[c+1], sSh[c+1]), 0.f));
    doc(acc, sW4, c+2, fmaxf(fmaf(v.z, sSc[c+2], sSh[c+2]), 0.f));
    doc(acc, sW4, c+3, fmaxf(fmaf(v.w, sSc[c+3], sSh[c+3]), 0.f));
  }
#pragma unroll
  for (int o4 = 0; o4 < 16; ++o4)
    Y4[o4] = make_float4(acc[o4*4], acc[o4*4+1], acc[o4*4+2], acc[o4*4+3]);
  wave_stats64(acc, sStat, tid);
  __syncthreads();
  if (tid < 128) atomicAdd(&stats[128+tid], sStat[tid]);
}

// ---------------- layer 2: BN+relu + conv(64->128) + stats + max/min pool ----------------
__global__ __launch_bounds__(256) void k_layer2(
    const float* __restrict__ y, const float* __restrict__ W,
    const float* __restrict__ bias, float* stats,
    float* __restrict__ pmax, float* __restrict__ pmin) {
  __shared__ float4 sW4[64*32];
  __shared__ float sB[128], sSc[64], sSh[64];
  __shared__ float sStat[256];
  float* sW = (float*)sW4;
  int tid = threadIdx.x;
  for (int i = tid; i < 64*128; i += 256) {
    int c = i >> 7, o = i & 127;
    sW[i] = W[o*64 + c];
  }
  if (tid < 128) sB[tid] = bias[tid];
  if (tid < 64) { sSc[tid] = stats[640+tid]; sSh[tid] = stats[704+tid]; }
  sStat[tid] = 0.f;
  __syncthreads();
  int t = blockIdx.x*256 + tid;
  int g = t >> 4;
  int o0 = (t & 15) * 8;
  int w0i = o0 >> 2;
  float mx[8], mn[8], sm[8], sq[8];
#pragma unroll
  for (int i=0;i<8;++i){ mx[i]=-3.4e38f; mn[i]=3.4e38f; sm[i]=0.f; sq[i]=0.f; }
  const float4* Y4 = (const float4*)(y) + (size_t)g*32*16;
#pragma unroll 1
  for (int rb = 0; rb < 8; ++rb) {
    float a[4][8];
#pragma unroll
    for (int j=0;j<4;++j)
#pragma unroll
      for (int i=0;i<8;++i) a[j][i] = sB[o0+i];
#pragma unroll
    for (int c4 = 0; c4 < 16; ++c4) {
      float4 w[8];
#pragma unroll
      for (int ch = 0; ch < 4; ++ch) {
        w[ch*2]   = sW4[(c4*4+ch)*32 + w0i];
        w[ch*2+1] = sW4[(c4*4+ch)*32 + w0i + 1];
      }
      float sc0=sSc[c4*4], sc1=sSc[c4*4+1], sc2=sSc[c4*4+2], sc3=sSc[c4*4+3];
      float sh0=sSh[c4*4], sh1=sSh[c4*4+1], sh2=sSh[c4*4+2], sh3=sSh[c4*4+3];
#pragma unroll
      for (int j = 0; j < 4; ++j) {
        float4 v = Y4[(rb*4+j)*16 + c4];
        float r0 = fmaxf(fmaf(v.x, sc0, sh0), 0.f);
        float r1 = fmaxf(fmaf(v.y, sc1, sh1), 0.f);
        float r2 = fmaxf(fmaf(v.z, sc2, sh2), 0.f);
        float r3 = fmaxf(fmaf(v.w, sc3, sh3), 0.f);
        a[j][0]=fmaf(r0,w[0].x,a[j][0]); a[j][1]=fmaf(r0,w[0].y,a[j][1]);
        a[j][2]=fmaf(r0,w[0].z,a[j][2]); a[j][3]=fmaf(r0,w[0].w,a[j][3]);
        a[j][4]=fmaf(r0,w[1].x,a[j][4]); a[j][5]=fmaf(r0,w[1].y,a[j][5]);
        a[j][6]=fmaf(r0,w[1].z,a[j][6]); a[j][7]=fmaf(r0,w[1].w,a[j][7]);
        a[j][0]=fmaf(r1,w[2].x,a[j][0]); a[j][1]=fmaf(r1,w[2].y,a[j][1]);
        a[j][2]=fmaf(r1,w[2].z,a[j][2]); a[j][3]=fmaf(r1,w[2].w,a[j][3]);
        a[j][4]=fmaf(r1,w[3].x,a[j][4]); a[j][5]=fmaf(r1,w[3].y,a[j][5]);
        a[j][6]=fmaf(r1,w[3].z,a[j][6]); a[j][7]=fmaf(r1,w[3].w,a[j][7]);
        a[j][0]=fmaf(r2,w[4].x,a[j][0]); a[j][1]=fmaf(r2,w[4].y,a[j][1]);
        a[j][2]=fmaf(r2,w[4].z,a[j][2]); a[j][3]=fmaf(r2,w[4].w,a[j][3]);
        a[j][4]=fmaf(r2,w[5].x,a[j][4]); a[j][5]=fmaf(r2,w[5].y,a[j][5]);
        a[j][6]=fmaf(r2,w[5].z,a[j][6]); a[j][7]=fmaf(r2,w[5].w,a[j][7]);
        a[j][0]=fmaf(r3,w[6].x,a[j][0]); a[j][1]=fmaf(r3,w[6].y,a[j][1]);
        a[j][2]=fmaf(r3,w[6].z,a[j][2]); a[j][3]=fmaf(r3,w[6].w,a[j][3]);
        a[j][4]=fmaf(r3,w[7].x,a[j][4]); a[j][5]=fmaf(r3,w[7].y,a[j][5]);
        a[j][6]=fmaf(r3,w[7].z,a[j][6]); a[j][7]=fmaf(r3,w[7].w,a[j][7]);
      }
    }
#pragma unroll
    for (int j = 0; j < 4; ++j)
#pragma unroll
      for (int i = 0; i < 8; ++i) {
        float av = a[j][i];
        mx[i]=fmaxf(mx[i],av); mn[i]=fminf(mn[i],av);
        sm[i]=fadd_(sm[i],av); sq[i]=fmaf(av,av,sq[i]);
      }
  }
  size_t ob = (size_t)g*128 + o0;
#pragma unroll
  for (int i=0;i<8;++i) { pmax[ob+i]=mx[i]; pmin[ob+i]=mn[i]; }
#pragma unroll
  for (int i=0;i<8;++i) {
    atomicAdd(&sStat[o0+i], sm[i]);
    atomicAdd(&sStat[128+o0+i], sq[i]);
  }
  __syncthreads();
  atomicAdd(&stats[256+tid], sStat[tid]);
}

// ---------------- BN finalize ----------------
__global__ void k_fin(float* stats, const float* g, const float* bb,
                      int cout, int soff, int ooff) {
  int o = threadIdx.x;
  if (o >= cout) return;
  float s = stats[soff + o], s2 = stats[soff + cout + o];
  float mean = s * (1.0f/262144.0f);
  float var = fmaxf(s2 * (1.0f/262144.0f) - mean*mean, 0.f);
  float sc = g[o] / sqrtf(var + 1e-5f);
  stats[ooff + o] = sc;
  stats[ooff + cout + o] = bb[o] - mean * sc;
}

// ---------------- output: BN+relu on pooled ----------------
__global__ __launch_bounds__(256) void k_out(const float* __restrict__ pmax,
    const float* __restrict__ pmin, const float* __restrict__ stats,
    float* __restrict__ outp) {
  int t = blockIdx.x*256 + threadIdx.x;
  int o = t & 127;
  float sc = stats[768+o], sh = stats[896+o];
  float sel = (sc >= 0.f) ? pmax[t] : pmin[t];
  outp[t] = fmaxf(fmaf(sel, sc, sh), 0.f);
}

extern "C" void kernel_launch(void* const* d_in, const int* in_sizes, int n_in,
                              void* d_out, int out_size, void* d_ws, size_t ws_size,
                              hipStream_t stream) {
  const float* xyz = (const float*)d_in[0];
  const float* pts = (const float*)d_in[1];
  const float* W0  = (const float*)d_in[2];
  const float* b0  = (const float*)d_in[3];
  const float* g0  = (const float*)d_in[4];
  const float* bb0 = (const float*)d_in[5];
  const float* W1  = (const float*)d_in[6];
  const float* b1  = (const float*)d_in[7];
  const float* g1  = (const float*)d_in[8];
  const float* bb1 = (const float*)d_in[9];
  const float* W2  = (const float*)d_in[10];
  const float* b2  = (const float*)d_in[11];
  const float* g2  = (const float*)d_in[12];
  const float* bb2 = (const float*)d_in[13];
  float* out_nx = (float*)d_out;
  float* out_np = out_nx + (size_t)NB*NS*3;
  float* ws = (float*)d_ws;
  float* stats = ws;                               // 1024 floats
  int* gidx = (int*)(ws + 1024);                   // NROWS ints
  float* ybuf = ws + 1024 + NROWS;                 // NROWS*64 floats
  float* pmax = ybuf + (size_t)NROWS*64;           // NB*NS*128
  float* pmin = pmax + (size_t)NB*NS*128;          // NB*NS*128

  k_init<<<1, 1024, 0, stream>>>(stats);
  k_fps<<<NB, 256, 0, stream>>>(xyz, out_nx);
  k_query<<<2048, 256, 0, stream>>>(xyz, out_nx, gidx);
  k_layer0<<<1024, 256, 0, stream>>>(xyz, pts, out_nx, gidx, W0, b0, ybuf, stats);
  k_fin<<<1, 128, 0, stream>>>(stats, g0, bb0, 64, 0, 512);
  k_layer1<<<1024, 256, 0, stream>>>(ybuf, W1, b1, stats);
  k_fin<<<1, 128, 0, stream>>>(stats, g1, bb1, 64, 128, 640);
  k_layer2<<<512, 256, 0, stream>>>(ybuf, W2, b2, stats, pmax, pmin);
  k_fin<<<1, 128, 0, stream>>>(stats, g2, bb2, 128, 256, 768);
  k_out<<<4096, 256, 0, stream>>>(pmax, pmin, stats, out_np);
}